// Round 9
// baseline (380.562 us; speedup 1.0000x reference)
//
#include <hip/hip_runtime.h>
#include <math.h>

// Problem constants
#define BATCH 262144

// ws layout (float offsets)
#define WF_OFF  0        // [72][256] gate-interleaved fused weights: W_fused[k][u*4+g]
#define BF_OFF  18432    // [256] gate-interleaved bias b_fused[u*4+g]
#define G6_OFF  18944    // [8][8]  C^T diag(1/(R+1e-6)) C
#define G8_OFF  19008    // [8][8]  C^T diag(1/(R+1e-8)) C
#define R6_OFF  19072    // [16] 1/(R+1e-6)
#define R8_OFF  19088    // [16] 1/(R+1e-8)
#define SLR_OFF 19104    // scalar: sum log(R+1e-6)

__device__ __forceinline__ float rcp1(float x) {
    float r = __builtin_amdgcn_rcpf(x);
    return r * (2.0f - x * r);   // one Newton step: ~1e-7 rel err
}
__device__ __forceinline__ float sigm(float x) {
    float e = __expf(-fabsf(x));          // in (0,1], never overflows
    float s = rcp1(1.0f + e);             // sigm(|x|)
    return (x >= 0.0f) ? s : e * s;       // sigm(-|x|) = e*s
}
__device__ __forceinline__ float tanh_f(float x) {
    float e = __expf(-2.0f * fabsf(x));   // in (0,1]
    float t = (1.0f - e) * rcp1(1.0f + e);
    return copysignf(t, x);
}

// ---------------- prep: fuse/permute weights + batch-independent stats -------
__global__ void prep_kernel(const float* __restrict__ Wk,   // [8][256]
                            const float* __restrict__ Wr,   // [64][256]
                            const float* __restrict__ b_lstm,// [256]
                            const float* __restrict__ Cm,   // [16][8]
                            const float* __restrict__ logR, // [16]
                            float* __restrict__ ws) {
    int t = threadIdx.x;   // 0..255 = fused column c = u*4 + g
    int src = (t & 3) * 64 + (t >> 2);   // original column g*64+u
#pragma unroll
    for (int k = 0; k < 8; ++k)  ws[WF_OFF + k * 256 + t]       = Wk[k * 256 + src];
#pragma unroll
    for (int k = 0; k < 64; ++k) ws[WF_OFF + (8 + k) * 256 + t] = Wr[k * 256 + src];
    ws[BF_OFF + t] = b_lstm[src];

    if (t < 64) {
        int k = t >> 3, l = t & 7;
        float g6 = 0.0f, g8 = 0.0f;
        for (int i = 0; i < 16; ++i) {
            float R  = expf(logR[i]);
            float cc = Cm[i * 8 + k] * Cm[i * 8 + l];
            g6 += cc / (R + 1e-6f);
            g8 += cc / (R + 1e-8f);
        }
        ws[G6_OFF + t] = g6;
        ws[G8_OFF + t] = g8;
    } else if (t < 80) {
        int i = t - 64;
        float R = expf(logR[i]);
        ws[R6_OFF + i] = 1.0f / (R + 1e-6f);
        ws[R8_OFF + i] = 1.0f / (R + 1e-8f);
    } else if (t == 80) {
        float s = 0.0f;
        for (int i = 0; i < 16; ++i) s += logf(expf(logR[i]) + 1e-6f);
        ws[SLR_OFF] = s;
    }
}

// ---------------- fused kernel: LSTM GEMM + nonlin + Gaussian tail -----------
// Block = 256 threads, 64 elements. GEMM: per-thread 8x8, u0=nt, u1=nt+32
// (linear B-reads, conflict-free, r5-verified). W double-buffered: loads for
// chunk ch+1 issued pre-barrier, ds_write post-compute -> 1 barrier/chunk.
// Tail fused: h_new stays in LDS (col-major [u][65]); t<64 computes
// mu/lsg + Woodbury alpha + posterior V; V staged through LDS for coalesced
// writes. No h_new HBM round-trip, no second big kernel.
__global__ __launch_bounds__(256)
void fused_kernel(const float* __restrict__ h_in,
                  const float* __restrict__ c_in,
                  const float* __restrict__ z_prev,
                  const float* __restrict__ x_in,
                  const float* __restrict__ W_mu,
                  const float* __restrict__ b_mu,
                  const float* __restrict__ W_ls,
                  const float* __restrict__ b_ls,
                  const float* __restrict__ Cm,
                  const float* __restrict__ b_em,
                  const float* __restrict__ ws,
                  float* __restrict__ out) {
    __shared__ __align__(16) float ha_lds[64 * 72];    // [e][k] z+h in; -> cbuf[64][64]; -> vbuf[64][65] (4160<=4608)
    __shared__ __align__(16) float w_lds[2 * 12 * 256];// W dbuf; -> hbuf[64*65] (4160<=6144)

    const int t  = threadIdx.x;
    const int mt = t >> 5;     // 0..7
    const int nt = t & 31;     // 0..31
    const int u0 = nt;
    const int u1 = nt + 32;
    const size_t E0 = (size_t)blockIdx.x * 64;
    const float* WF = ws + WF_OFF;

    // ---- stage ha row-major (linear float4 LDS writes) ----
#pragma unroll
    for (int i = 0; i < 4; ++i) {
        int g = i * 1024 + t * 4;      // 0..4095
        int e = g >> 6, u = g & 63;
        float4 hv = *(const float4*)(h_in + E0 * 64 + g);
        *(float4*)(ha_lds + e * 72 + 8 + u) = hv;
    }
    if (t < 128) {
        int g = t * 4;                 // 0..511
        int e = g >> 3, p = g & 7;
        float4 zv = *(const float4*)(z_prev + E0 * 8 + g);
        *(float4*)(ha_lds + e * 72 + p) = zv;
    }

    float acc[8][8];
#pragma unroll
    for (int j = 0; j < 8; ++j)
#pragma unroll
        for (int c = 0; c < 8; ++c) acc[j][c] = 0.0f;

    // ---- prologue: chunk 0 -> buf 0 ----
    float4 wr0, wr1, wr2;
    {
        wr0 = *(const float4*)(WF + (0 * 256 + t) * 4);
        wr1 = *(const float4*)(WF + (1 * 256 + t) * 4);
        wr2 = *(const float4*)(WF + (2 * 256 + t) * 4);
        *(float4*)(w_lds + (0 * 256 + t) * 4) = wr0;
        *(float4*)(w_lds + (1 * 256 + t) * 4) = wr1;
        *(float4*)(w_lds + (2 * 256 + t) * 4) = wr2;
    }

    // ---- GEMM over K: 6 chunks of 12, double-buffered, 1 barrier/chunk ----
#pragma unroll 1
    for (int ch = 0; ch < 6; ++ch) {
        const int cur = ch & 1;
        if (ch < 5) {   // issue next-chunk loads early (latency hides under compute)
            const float* src = WF + (ch + 1) * 3072;
            wr0 = *(const float4*)(src + (0 * 256 + t) * 4);
            wr1 = *(const float4*)(src + (1 * 256 + t) * 4);
            wr2 = *(const float4*)(src + (2 * 256 + t) * 4);
        }
        __syncthreads();   // buf[cur] ready (writes from prev iter / prologue)
        const float* wb = w_lds + cur * 3072;
#pragma unroll
        for (int k4 = 0; k4 < 12; k4 += 4) {
            float4 av[8];
#pragma unroll
            for (int j = 0; j < 8; ++j)
                av[j] = *(const float4*)(ha_lds + (mt * 8 + j) * 72 + ch * 12 + k4);
#pragma unroll
            for (int kk = 0; kk < 4; ++kk) {
                float4 b0 = *(const float4*)(wb + (k4 + kk) * 256 + u0 * 4);
                float4 b1 = *(const float4*)(wb + (k4 + kk) * 256 + u1 * 4);
#pragma unroll
                for (int j = 0; j < 8; ++j) {
                    float a = (kk == 0) ? av[j].x : (kk == 1) ? av[j].y : (kk == 2) ? av[j].z : av[j].w;
                    acc[j][0] = fmaf(a, b0.x, acc[j][0]);
                    acc[j][1] = fmaf(a, b0.y, acc[j][1]);
                    acc[j][2] = fmaf(a, b0.z, acc[j][2]);
                    acc[j][3] = fmaf(a, b0.w, acc[j][3]);
                    acc[j][4] = fmaf(a, b1.x, acc[j][4]);
                    acc[j][5] = fmaf(a, b1.y, acc[j][5]);
                    acc[j][6] = fmaf(a, b1.z, acc[j][6]);
                    acc[j][7] = fmaf(a, b1.w, acc[j][7]);
                }
            }
        }
        if (ch < 5) {   // write next chunk into the other buffer
            float* dst = w_lds + (1 - cur) * 3072;
            *(float4*)(dst + (0 * 256 + t) * 4) = wr0;
            *(float4*)(dst + (1 * 256 + t) * 4) = wr1;
            *(float4*)(dst + (2 * 256 + t) * 4) = wr2;
        }
    }
    __syncthreads();   // all GEMM reads done; ha_lds / w_lds reusable

    // ---- stage c_old into cbuf (short live range) ----
    float* cbuf = ha_lds;    // [64][64] row-major
    float* hbuf = w_lds;     // [u][65] col-major h_new
    {
        float4 c0 = *(const float4*)(c_in + E0 * 64 + 0 * 1024 + t * 4);
        float4 c1 = *(const float4*)(c_in + E0 * 64 + 1 * 1024 + t * 4);
        float4 c2 = *(const float4*)(c_in + E0 * 64 + 2 * 1024 + t * 4);
        float4 c3 = *(const float4*)(c_in + E0 * 64 + 3 * 1024 + t * 4);
        *(float4*)(cbuf + 0 * 1024 + t * 4) = c0;
        *(float4*)(cbuf + 1 * 1024 + t * 4) = c1;
        *(float4*)(cbuf + 2 * 1024 + t * 4) = c2;
        *(float4*)(cbuf + 3 * 1024 + t * 4) = c3;
    }
    __syncthreads();

    // ---- nonlinearity: thread owns (u0,u1) x elems mt*8..+7 ----
    const float* BF = ws + BF_OFF;
    const float bi0 = BF[u0 * 4 + 0], bf0 = BF[u0 * 4 + 1], bg0 = BF[u0 * 4 + 2], bo0 = BF[u0 * 4 + 3];
    const float bi1 = BF[u1 * 4 + 0], bf1 = BF[u1 * 4 + 1], bg1 = BF[u1 * 4 + 2], bo1 = BF[u1 * 4 + 3];
#pragma unroll
    for (int j = 0; j < 8; ++j) {
        int e = mt * 8 + j;
        {
            float zi = acc[j][0] + bi0, zf = acc[j][1] + bf0;
            float zg = acc[j][2] + bg0, zo = acc[j][3] + bo0;
            float cold = cbuf[e * 64 + u0];
            float cn = sigm(zf) * cold + sigm(zi) * tanh_f(zg);
            cbuf[e * 64 + u0] = cn;                 // own slot
            hbuf[u0 * 65 + e] = sigm(zo) * tanh_f(cn);
        }
        {
            float zi = acc[j][4] + bi1, zf = acc[j][5] + bf1;
            float zg = acc[j][6] + bg1, zo = acc[j][7] + bo1;
            float cold = cbuf[e * 64 + u1];
            float cn = sigm(zf) * cold + sigm(zi) * tanh_f(zg);
            cbuf[e * 64 + u1] = cn;
            hbuf[u1 * 65 + e] = sigm(zo) * tanh_f(cn);
        }
    }
    __syncthreads();

    // ---- coalesced write-out of c_new (linear) and h_new (col-major gather) ----
    float* outH = out + (size_t)BATCH * 73  + E0 * 64;
    float* outC = out + (size_t)BATCH * 137 + E0 * 64;
#pragma unroll
    for (int i = 0; i < 4; ++i) {
        int g = i * 1024 + t * 4;
        *(float4*)(outC + g) = *(const float4*)(cbuf + g);
        int e = g >> 6, u = g & 63;
        float4 hv = make_float4(hbuf[(u + 0) * 65 + e], hbuf[(u + 1) * 65 + e],
                                hbuf[(u + 2) * 65 + e], hbuf[(u + 3) * 65 + e]);
        *(float4*)(outH + g) = hv;
    }
    __syncthreads();   // cbuf reads done -> ha_lds free for V staging

    // ---- Gaussian tail: t<64, element e = E0 + t ----
    float* vbuf = ha_lds;    // [64 (a*8+b)][65] col-major over elements
    if (t < 64) {
        const float* G6 = ws + G6_OFF;
        const float* G8 = ws + G8_OFF;
        const float* r6 = ws + R6_OFF;
        const float* r8 = ws + R8_OFF;
        const float  slr = ws[SLR_OFF];
        const size_t eg = E0 + t;

        // mu / log_sigma from LDS h_new (conflict-free col-major reads)
        float mu[8], lsg[8];
#pragma unroll
        for (int d = 0; d < 8; ++d) { mu[d] = b_mu[d]; lsg[d] = b_ls[d]; }
#pragma unroll
        for (int u = 0; u < 64; ++u) {
            float hv = hbuf[u * 65 + t];
#pragma unroll
            for (int d = 0; d < 8; ++d) {
                mu[d]  = fmaf(hv, W_mu[u * 8 + d], mu[d]);
                lsg[d] = fmaf(hv, W_ls[u * 8 + d], lsg[d]);
            }
        }

        float sig[8], Sinv[8];
#pragma unroll
        for (int d = 0; d < 8; ++d) {
            float l = fminf(fmaxf(lsg[d], -5.0f), 3.0f);
            float s = __expf(l);
            sig[d]  = s;
            Sinv[d] = rcp1(s * s + 1e-8f);
        }

        float xv[16];
        {
            const float4* x4 = (const float4*)(x_in + eg * 16);
#pragma unroll
            for (int q = 0; q < 4; ++q) {
                float4 v = x4[q];
                xv[4 * q + 0] = v.x; xv[4 * q + 1] = v.y;
                xv[4 * q + 2] = v.z; xv[4 * q + 3] = v.w;
            }
        }

        float t6[8], t8[8];
#pragma unroll
        for (int k = 0; k < 8; ++k) { t6[k] = 0.0f; t8[k] = 0.0f; }
        float qdr = 0.0f;
#pragma unroll
        for (int i = 0; i < 16; ++i) {
            float pm = b_em[i];
#pragma unroll
            for (int d = 0; d < 8; ++d) pm = fmaf(mu[d], Cm[i * 8 + d], pm);
            float df = xv[i] - pm;
            float xe = xv[i] - b_em[i];
            float a6 = df * r6[i];
            float a8 = xe * r8[i];
            qdr = fmaf(df, a6, qdr);
#pragma unroll
            for (int k = 0; k < 8; ++k) {
                t6[k] = fmaf(a6, Cm[i * 8 + k], t6[k]);
                t8[k] = fmaf(a8, Cm[i * 8 + k], t8[k]);
            }
        }

        // alpha via Woodbury: M = I + sig sig^T (.) G6
        float M[8][8];
#pragma unroll
        for (int k = 0; k < 8; ++k)
#pragma unroll
            for (int l = 0; l <= k; ++l)
                M[k][l] = ((k == l) ? 1.0f : 0.0f) + sig[k] * sig[l] * G6[k * 8 + l];

        float ldia[8];
        float logdetM = 0.0f;
#pragma unroll
        for (int k = 0; k < 8; ++k) {
            float d = M[k][k];
#pragma unroll
            for (int j = 0; j < k; ++j) d = fmaf(-M[k][j], M[k][j], d);
            float l = sqrtf(d);
            logdetM += __logf(d);
            float li = rcp1(l);
            M[k][k] = l; ldia[k] = li;
#pragma unroll
            for (int i = k + 1; i < 8; ++i) {
                float s = M[i][k];
#pragma unroll
                for (int j = 0; j < k; ++j) s = fmaf(-M[i][j], M[k][j], s);
                M[i][k] = s * li;
            }
        }
        float w[8];
        float ssq = 0.0f;
#pragma unroll
        for (int k = 0; k < 8; ++k) {
            float s = sig[k] * t6[k];
#pragma unroll
            for (int j = 0; j < k; ++j) s = fmaf(-M[k][j], w[j], s);
            w[k] = s * ldia[k];
            ssq  = fmaf(w[k], w[k], ssq);
        }
        float mahal  = qdr - ssq;
        float alpha  = -0.5f * (mahal + slr + logdetM + 29.40603306254952f); // 16*ln(2pi)

        // gamma: V = (diag(Sinv)+1e-6 I + G8)^-1
        float Vi[8][8];
#pragma unroll
        for (int k = 0; k < 8; ++k)
#pragma unroll
            for (int l = 0; l <= k; ++l)
                Vi[k][l] = G8[k * 8 + l] + ((k == l) ? (Sinv[k] + 1e-6f) : 0.0f);

        float vdia[8];
#pragma unroll
        for (int k = 0; k < 8; ++k) {
            float d = Vi[k][k];
#pragma unroll
            for (int j = 0; j < k; ++j) d = fmaf(-Vi[k][j], Vi[k][j], d);
            float l = sqrtf(d);
            float li = rcp1(l);
            Vi[k][k] = l; vdia[k] = li;
#pragma unroll
            for (int i = k + 1; i < 8; ++i) {
                float s = Vi[i][k];
#pragma unroll
                for (int j = 0; j < k; ++j) s = fmaf(-Vi[i][j], Vi[k][j], s);
                Vi[i][k] = s * li;
            }
        }
        // J = L^-1 (lower), stored into M (dead)
#pragma unroll
        for (int k = 0; k < 8; ++k) {
            M[k][k] = vdia[k];
#pragma unroll
            for (int i = k + 1; i < 8; ++i) {
                float s = 0.0f;
#pragma unroll
                for (int j = k; j < i; ++j) s = fmaf(Vi[i][j], M[j][k], s);
                M[i][k] = -s * vdia[i];
            }
        }
        float info[8];
#pragma unroll
        for (int k = 0; k < 8; ++k) info[k] = fmaf(Sinv[k], mu[k], t8[k]);

        // V = J^T J -> vbuf; gamma = V @ info
        float gam[8];
#pragma unroll
        for (int a = 0; a < 8; ++a) gam[a] = 0.0f;
#pragma unroll
        for (int a = 0; a < 8; ++a) {
#pragma unroll
            for (int b = 0; b < 8; ++b) {
                int m0 = (a > b) ? a : b;
                float s = 0.0f;
#pragma unroll
                for (int i = 0; i < 8; ++i)
                    if (i >= m0) s = fmaf(M[i][a], M[i][b], s);
                vbuf[(a * 8 + b) * 65 + t] = s;
                gam[a] = fmaf(s, info[b], gam[a]);
            }
        }
        out[eg] = alpha;
        float4* outG = (float4*)(out + (size_t)BATCH + eg * 8);
        outG[0] = make_float4(gam[0], gam[1], gam[2], gam[3]);
        outG[1] = make_float4(gam[4], gam[5], gam[6], gam[7]);
    }
    __syncthreads();

    // ---- coalesced V write-out (col-major gather, r1-proven pattern) ----
    {
        float* outV = out + (size_t)BATCH * 9 + E0 * 64;
#pragma unroll
        for (int i = 0; i < 4; ++i) {
            int g = i * 1024 + t * 4;
            int ee = g >> 6, j = g & 63;
            float4 v = make_float4(vbuf[(j + 0) * 65 + ee], vbuf[(j + 1) * 65 + ee],
                                   vbuf[(j + 2) * 65 + ee], vbuf[(j + 3) * 65 + ee]);
            *(float4*)(outV + g) = v;
        }
    }
}

extern "C" void kernel_launch(void* const* d_in, const int* in_sizes, int n_in,
                              void* d_out, int out_size, void* d_ws, size_t ws_size,
                              hipStream_t stream) {
    const float* h    = (const float*)d_in[0];
    const float* c    = (const float*)d_in[1];
    const float* zp   = (const float*)d_in[2];
    const float* xt   = (const float*)d_in[3];
    const float* Wk   = (const float*)d_in[4];
    const float* Wr   = (const float*)d_in[5];
    const float* bl   = (const float*)d_in[6];
    const float* Wmu  = (const float*)d_in[7];
    const float* bmu  = (const float*)d_in[8];
    const float* Wls  = (const float*)d_in[9];
    const float* bls  = (const float*)d_in[10];
    const float* Cm   = (const float*)d_in[11];
    const float* bem  = (const float*)d_in[12];
    const float* logR = (const float*)d_in[13];
    float* ws  = (float*)d_ws;
    float* out = (float*)d_out;

    hipLaunchKernelGGL(prep_kernel, dim3(1), dim3(256), 0, stream, Wk, Wr, bl, Cm, logR, ws);
    hipLaunchKernelGGL(fused_kernel, dim3(BATCH / 64), dim3(256), 0, stream,
                       h, c, zp, xt, Wmu, bmu, Wls, bls, Cm, bem, ws, out);
}

// Round 10
// 148.365 us; speedup vs baseline: 2.5650x; 2.5650x over previous
//
#include <hip/hip_runtime.h>
#include <math.h>

// Problem constants
#define BATCH 262144

// ws layout (float offsets)
#define WA_OFF  0        // [48 frags][64 lanes][8 bf16] A-fragments of W^T (12288 floats)
#define G6_OFF  18944    // [8][8]  C^T diag(1/(R+1e-6)) C
#define G8_OFF  19008    // [8][8]  C^T diag(1/(R+1e-8)) C
#define R6_OFF  19072    // [16] 1/(R+1e-6)
#define R8_OFF  19088    // [16] 1/(R+1e-8)
#define SLR_OFF 19104    // scalar: sum log(R+1e-6)

typedef __attribute__((ext_vector_type(8))) short bf16x8;
typedef __attribute__((ext_vector_type(4))) float f32x4;

__device__ __forceinline__ float rcp1(float x) {
    float r = __builtin_amdgcn_rcpf(x);
    return r * (2.0f - x * r);
}
__device__ __forceinline__ float sigm(float x) {
    float e = __expf(-fabsf(x));
    float s = rcp1(1.0f + e);
    return (x >= 0.0f) ? s : e * s;
}
__device__ __forceinline__ float tanh_f(float x) {
    float e = __expf(-2.0f * fabsf(x));
    float t = (1.0f - e) * rcp1(1.0f + e);
    return copysignf(t, x);
}
__device__ __forceinline__ unsigned rne_bf16(float x) {
    unsigned u = __float_as_uint(x);
    return (u + 0x7fffu + ((u >> 16) & 1u)) >> 16;   // round-to-nearest-even bf16
}
__device__ __forceinline__ unsigned pack2(float lo, float hi) {
    return rne_bf16(lo) | (rne_bf16(hi) << 16);
}

// ---------------- prep: A-fragments (bf16) + batch-independent stats ---------
// A = W^T (M=256 gate-interleaved cols, K=96 padded). MFMA A-frag layout
// (AMD lab-notes convention): lane l holds A[row = m*16 + (l&15)]
// [k = ks*32 + (l>>4)*8 + j], j=0..7. Fragment-major: WA[(m*3+ks)*64 + l][8].
__global__ void prep_kernel(const float* __restrict__ Wk,   // [8][256]
                            const float* __restrict__ Wr,   // [64][256]
                            const float* __restrict__ Cm,   // [16][8]
                            const float* __restrict__ logR, // [16]
                            float* __restrict__ ws) {
    int t = threadIdx.x;
    unsigned* wa = (unsigned*)(ws + WA_OFF);
#pragma unroll 1
    for (int i = 0; i < 12; ++i) {
        int F  = i * 256 + t;          // 0..3071 = frag(48) x lane(64)
        int fr = F >> 6, l = F & 63;
        int m  = fr / 3, ks = fr % 3;
        int c  = m * 16 + (l & 15);    // gate-interleaved col = u*4+g
        int k0 = ks * 32 + (l >> 4) * 8;
        int src = (c & 3) * 64 + (c >> 2);   // original col g*64+u
        float v[8];
#pragma unroll
        for (int j = 0; j < 8; ++j) {
            int k = k0 + j;
            v[j] = (k < 8) ? Wk[k * 256 + src] : (k < 72 ? Wr[(k - 8) * 256 + src] : 0.0f);
        }
        wa[F * 4 + 0] = pack2(v[0], v[1]);
        wa[F * 4 + 1] = pack2(v[2], v[3]);
        wa[F * 4 + 2] = pack2(v[4], v[5]);
        wa[F * 4 + 3] = pack2(v[6], v[7]);
    }

    if (t < 64) {
        int k = t >> 3, l = t & 7;
        float g6 = 0.0f, g8 = 0.0f;
        for (int i = 0; i < 16; ++i) {
            float R  = expf(logR[i]);
            float cc = Cm[i * 8 + k] * Cm[i * 8 + l];
            g6 += cc / (R + 1e-6f);
            g8 += cc / (R + 1e-8f);
        }
        ws[G6_OFF + t] = g6;
        ws[G8_OFF + t] = g8;
    } else if (t < 80) {
        int i = t - 64;
        float R = expf(logR[i]);
        ws[R6_OFF + i] = 1.0f / (R + 1e-6f);
        ws[R8_OFF + i] = 1.0f / (R + 1e-8f);
    } else if (t == 80) {
        float s = 0.0f;
        for (int i = 0; i < 16; ++i) s += logf(expf(logR[i]) + 1e-6f);
        ws[SLR_OFF] = s;
    }
}

// ---------------- LSTM kernel: MFMA bf16 GEMM --------------------------------
// Block = 256 thr = 4 waves, 64 elements. D[c][e] = W^T ha^T: M=256 N=64 K=96.
// Wave w: M-tiles m=4w..4w+3 (units 16w..16w+15). Per wave 4m x 4n x 3k = 48
// mfma_f32_16x16x32_bf16, acc 4 f32/tile. D layout (m89): row=(l>>4)*4+r,
// col=l&15 -> lane r-regs = the 4 gates (i,f,g,o) of unit u=16w+4mm+(l>>4)
// for element e=n*16+(l&15). Nonlinearity fully in-register, no exchange.
__global__ __launch_bounds__(256)
void lstm_kernel(const float* __restrict__ h_in,
                 const float* __restrict__ c_in,
                 const float* __restrict__ z_prev,
                 const float* __restrict__ b_lstm,
                 const float* __restrict__ ws,
                 float* __restrict__ out) {
    __shared__ __align__(16) float r1[64 * 72];  // ha fp32 [e][72]; -> cbuf [e][68]
    __shared__ __align__(16) float r2[64 * 68];  // B-frags (3072 floats); -> hbuf [u][68]

    const int t   = threadIdx.x;
    const int l   = t & 63;
    const int wvu = __builtin_amdgcn_readfirstlane(t >> 6);
    const int lhi = l >> 4, llo = l & 15;
    const size_t E0 = (size_t)blockIdx.x * 64;

    // ---- stage ha fp32 row-major (coalesced, linear LDS writes) ----
#pragma unroll
    for (int i = 0; i < 4; ++i) {
        int g = i * 1024 + t * 4;
        int e = g >> 6, u = g & 63;
        float4 hv = *(const float4*)(h_in + E0 * 64 + g);
        *(float4*)(r1 + e * 72 + 8 + u) = hv;
    }
    if (t < 128) {
        int g = t * 4;
        int e = g >> 3, p = g & 7;
        float4 zv = *(const float4*)(z_prev + E0 * 8 + g);
        *(float4*)(r1 + e * 72 + p) = zv;
    }
    __syncthreads();   // b1: ha staged

    // ---- convert ha -> bf16 B-fragments (linear 32B reads, scattered uint4 writes)
    // B-frag layout: lane l holds B[k=ks*32+(l>>4)*8+j][e = n*16+(l&15)],
    // fragment-major at F=(n*3+ks)*64+l.
    unsigned* fr = (unsigned*)r2;
#pragma unroll
    for (int i = 0; i < 3; ++i) {
        int c = i * 256 + t;
        if (c < 576) {                       // 576 chunks of 8 floats (k<72)
            int e = c / 9, k0 = (c % 9) * 8;
            float4 va = *(const float4*)(r1 + c * 8);
            float4 vb = *(const float4*)(r1 + c * 8 + 4);
            uint4 pk;
            pk.x = pack2(va.x, va.y);
            pk.y = pack2(va.z, va.w);
            pk.z = pack2(vb.x, vb.y);
            pk.w = pack2(vb.z, vb.w);
            int n = e >> 4, lo = e & 15, ks = k0 >> 5, hi = (k0 & 31) >> 3;
            int F = (n * 3 + ks) * 64 + hi * 16 + lo;
            *(uint4*)(fr + F * 4) = pk;
        }
    }
    if (t < 192) {                           // zero-pad k = 72..95
        int n = t / 48, r = t % 48;
        int hi = r / 16 + 1, lo = r & 15;
        int F = (n * 3 + 2) * 64 + hi * 16 + lo;
        *(uint4*)(fr + F * 4) = make_uint4(0, 0, 0, 0);
    }
    __syncthreads();   // b2: frags ready; r1 (ha) dead

    // ---- issue c_old loads (latency hides under GEMM) ----
    float4 cp0 = *(const float4*)(c_in + E0 * 64 + 0 * 1024 + t * 4);
    float4 cp1 = *(const float4*)(c_in + E0 * 64 + 1 * 1024 + t * 4);
    float4 cp2 = *(const float4*)(c_in + E0 * 64 + 2 * 1024 + t * 4);
    float4 cp3 = *(const float4*)(c_in + E0 * 64 + 3 * 1024 + t * 4);

    // ---- MFMA GEMM: K-outer, 48 mfma/wave ----
    f32x4 acc[4][4];
#pragma unroll
    for (int mm = 0; mm < 4; ++mm)
#pragma unroll
        for (int n = 0; n < 4; ++n) acc[mm][n] = (f32x4){0.f, 0.f, 0.f, 0.f};

    const unsigned* WA = (const unsigned*)(ws + WA_OFF);
#pragma unroll
    for (int ks = 0; ks < 3; ++ks) {
        bf16x8 bfr[4], afr[4];
#pragma unroll
        for (int n = 0; n < 4; ++n)
            bfr[n] = *(const bf16x8*)(fr + ((n * 3 + ks) * 64 + l) * 4);
#pragma unroll
        for (int mm = 0; mm < 4; ++mm)
            afr[mm] = *(const bf16x8*)(WA + (((4 * wvu + mm) * 3 + ks) * 64 + l) * 4);
#pragma unroll
        for (int mm = 0; mm < 4; ++mm)
#pragma unroll
            for (int n = 0; n < 4; ++n)
                acc[mm][n] = __builtin_amdgcn_mfma_f32_16x16x32_bf16(
                    afr[mm], bfr[n], acc[mm][n], 0, 0, 0);
    }

    // ---- write cbuf [e][68] (r1 reuse; 16B-aligned float4) ----
    float* cbuf = r1;
    {
        int g0 = t * 4;
        *(float4*)(cbuf + ((g0 >> 6)) * 68 + (g0 & 63)) = cp0;
        int g1 = 1024 + t * 4;
        *(float4*)(cbuf + ((g1 >> 6)) * 68 + (g1 & 63)) = cp1;
        int g2 = 2048 + t * 4;
        *(float4*)(cbuf + ((g2 >> 6)) * 68 + (g2 & 63)) = cp2;
        int g3 = 3072 + t * 4;
        *(float4*)(cbuf + ((g3 >> 6)) * 68 + (g3 & 63)) = cp3;
    }
    __syncthreads();   // b3: cbuf staged + all frag reads done

    // ---- nonlinearity: lane owns 4u x 4e x 4 gates ----
    float* hbuf = r2;   // [u][68]
#pragma unroll
    for (int mm = 0; mm < 4; ++mm) {
        int u = 16 * wvu + 4 * mm + lhi;
        float bi = b_lstm[u], bf_ = b_lstm[64 + u], bg = b_lstm[128 + u], bo = b_lstm[192 + u];
#pragma unroll
        for (int n = 0; n < 4; ++n) {
            int e = n * 16 + llo;
            float zi = acc[mm][n][0] + bi;
            float zf = acc[mm][n][1] + bf_;
            float zg = acc[mm][n][2] + bg;
            float zo = acc[mm][n][3] + bo;
            float cold = cbuf[e * 68 + u];
            float cn = sigm(zf) * cold + sigm(zi) * tanh_f(zg);
            float hn = sigm(zo) * tanh_f(cn);
            cbuf[e * 68 + u] = cn;        // own slot
            hbuf[u * 68 + e] = hn;
        }
    }
    __syncthreads();   // b4

    // ---- coalesced write-out ----
    float* outH = out + (size_t)BATCH * 73  + E0 * 64;
    float* outC = out + (size_t)BATCH * 137 + E0 * 64;
#pragma unroll
    for (int i = 0; i < 4; ++i) {
        int g = i * 1024 + t * 4;
        int e = g >> 6, u = g & 63;
        *(float4*)(outC + g) = *(const float4*)(cbuf + e * 68 + u);
        float4 hv = make_float4(hbuf[(u + 0) * 68 + e], hbuf[(u + 1) * 68 + e],
                                hbuf[(u + 2) * 68 + e], hbuf[(u + 3) * 68 + e]);
        *(float4*)(outH + g) = hv;
    }
}

// ---------------- tail kernel: mu/lsg GEMM + Gaussian tail (r7-proven) -------
__global__ __launch_bounds__(256)
void tail_kernel(const float* __restrict__ x_in,
                 const float* __restrict__ W_mu,
                 const float* __restrict__ b_mu,
                 const float* __restrict__ W_ls,
                 const float* __restrict__ b_ls,
                 const float* __restrict__ Cm,
                 const float* __restrict__ b_em,
                 const float* __restrict__ ws,
                 float* __restrict__ out) {
    __shared__ float hn[64 * 65];     // [u][e] h_new tile; reused as V chunk buffer
    __shared__ float muls[16 * 257];  // [d][e256]

    const int t    = threadIdx.x;
    const int lane = t & 63;
    const int wv   = t >> 6;
    const int wvu  = __builtin_amdgcn_readfirstlane(wv);
    const int blk  = blockIdx.x;
    const float* hN = out + (size_t)BATCH * 73;

    for (int tile = 0; tile < 4; ++tile) {
        const size_t E0 = (size_t)blk * 256 + (size_t)tile * 64;
#pragma unroll
        for (int i = 0; i < 4; ++i) {
            int g = i * 1024 + t * 4;
            int e = g >> 6, u = g & 63;
            float4 hv = *(const float4*)(hN + E0 * 64 + g);
            hn[(u + 0) * 65 + e] = hv.x;
            hn[(u + 1) * 65 + e] = hv.y;
            hn[(u + 2) * 65 + e] = hv.z;
            hn[(u + 3) * 65 + e] = hv.w;
        }
        __syncthreads();
        {
            int d0 = wvu * 2;
            float m0 = b_mu[d0], m1 = b_mu[d0 + 1];
            float l0 = b_ls[d0], l1 = b_ls[d0 + 1];
#pragma unroll
            for (int u = 0; u < 64; ++u) {
                float hv = hn[u * 65 + lane];
                m0 = fmaf(hv, W_mu[u * 8 + d0],     m0);
                m1 = fmaf(hv, W_mu[u * 8 + d0 + 1], m1);
                l0 = fmaf(hv, W_ls[u * 8 + d0],     l0);
                l1 = fmaf(hv, W_ls[u * 8 + d0 + 1], l1);
            }
            int col = tile * 64 + lane;
            muls[(d0 + 0) * 257 + col] = m0;
            muls[(d0 + 1) * 257 + col] = m1;
            muls[(8 + d0 + 0) * 257 + col] = l0;
            muls[(8 + d0 + 1) * 257 + col] = l1;
        }
        __syncthreads();
    }

    const float* G6 = ws + G6_OFF;
    const float* G8 = ws + G8_OFF;
    const float* r6 = ws + R6_OFF;
    const float* r8 = ws + R8_OFF;
    const float  slr = ws[SLR_OFF];
    const size_t e = (size_t)blk * 256 + t;

    float mu[8], lsg[8];
#pragma unroll
    for (int d = 0; d < 8; ++d) {
        mu[d]  = muls[d * 257 + t];
        lsg[d] = muls[(8 + d) * 257 + t];
    }

    float sig[8], Sinv[8];
#pragma unroll
    for (int d = 0; d < 8; ++d) {
        float l = fminf(fmaxf(lsg[d], -5.0f), 3.0f);
        float s = __expf(l);
        sig[d]  = s;
        Sinv[d] = rcp1(s * s + 1e-8f);
    }

    float xv[16];
    {
        const float4* x4 = (const float4*)(x_in + e * 16);
#pragma unroll
        for (int q = 0; q < 4; ++q) {
            float4 v = x4[q];
            xv[4 * q + 0] = v.x; xv[4 * q + 1] = v.y;
            xv[4 * q + 2] = v.z; xv[4 * q + 3] = v.w;
        }
    }

    float t6[8], t8[8];
#pragma unroll
    for (int k = 0; k < 8; ++k) { t6[k] = 0.0f; t8[k] = 0.0f; }
    float qdr = 0.0f;
#pragma unroll
    for (int i = 0; i < 16; ++i) {
        float pm = b_em[i];
#pragma unroll
        for (int d = 0; d < 8; ++d) pm = fmaf(mu[d], Cm[i * 8 + d], pm);
        float df = xv[i] - pm;
        float xe = xv[i] - b_em[i];
        float a6 = df * r6[i];
        float a8 = xe * r8[i];
        qdr = fmaf(df, a6, qdr);
#pragma unroll
        for (int k = 0; k < 8; ++k) {
            t6[k] = fmaf(a6, Cm[i * 8 + k], t6[k]);
            t8[k] = fmaf(a8, Cm[i * 8 + k], t8[k]);
        }
    }

    // ---- alpha via Woodbury ----
    float M[8][8];
#pragma unroll
    for (int k = 0; k < 8; ++k)
#pragma unroll
        for (int l = 0; l <= k; ++l)
            M[k][l] = ((k == l) ? 1.0f : 0.0f) + sig[k] * sig[l] * G6[k * 8 + l];

    float ldia[8];
    float logdetM = 0.0f;
#pragma unroll
    for (int k = 0; k < 8; ++k) {
        float d = M[k][k];
#pragma unroll
        for (int j = 0; j < k; ++j) d = fmaf(-M[k][j], M[k][j], d);
        float l = sqrtf(d);
        logdetM += __logf(d);
        float li = rcp1(l);
        M[k][k] = l; ldia[k] = li;
#pragma unroll
        for (int i = k + 1; i < 8; ++i) {
            float s = M[i][k];
#pragma unroll
            for (int j = 0; j < k; ++j) s = fmaf(-M[i][j], M[k][j], s);
            M[i][k] = s * li;
        }
    }
    float w[8];
    float ssq = 0.0f;
#pragma unroll
    for (int k = 0; k < 8; ++k) {
        float s = sig[k] * t6[k];
#pragma unroll
        for (int j = 0; j < k; ++j) s = fmaf(-M[k][j], w[j], s);
        w[k] = s * ldia[k];
        ssq  = fmaf(w[k], w[k], ssq);
    }
    float mahal  = qdr - ssq;
    float logdet = slr + logdetM;
    float alpha  = -0.5f * (mahal + logdet + 29.40603306254952f); // 16*ln(2pi)

    // ---- gamma: V = (diag(Sinv)+1e-6 I + G8)^-1 ----
    float Vi[8][8];
#pragma unroll
    for (int k = 0; k < 8; ++k)
#pragma unroll
        for (int l = 0; l <= k; ++l)
            Vi[k][l] = G8[k * 8 + l] + ((k == l) ? (Sinv[k] + 1e-6f) : 0.0f);

    float vdia[8];
#pragma unroll
    for (int k = 0; k < 8; ++k) {
        float d = Vi[k][k];
#pragma unroll
        for (int j = 0; j < k; ++j) d = fmaf(-Vi[k][j], Vi[k][j], d);
        float l = sqrtf(d);
        float li = rcp1(l);
        Vi[k][k] = l; vdia[k] = li;
#pragma unroll
        for (int i = k + 1; i < 8; ++i) {
            float s = Vi[i][k];
#pragma unroll
            for (int j = 0; j < k; ++j) s = fmaf(-Vi[i][j], Vi[k][j], s);
            Vi[i][k] = s * li;
        }
    }
    // J = L^-1 (lower), stored into M (dead)
#pragma unroll
    for (int k = 0; k < 8; ++k) {
        M[k][k] = vdia[k];
#pragma unroll
        for (int i = k + 1; i < 8; ++i) {
            float s = 0.0f;
#pragma unroll
            for (int j = k; j < i; ++j) s = fmaf(Vi[i][j], M[j][k], s);
            M[i][k] = -s * vdia[i];
        }
    }
    float info[8];
#pragma unroll
    for (int k = 0; k < 8; ++k) info[k] = fmaf(Sinv[k], mu[k], t8[k]);

    // ---- V = J^T J + gamma, staged through LDS (reuse hn) in 4 chunks ----
    __syncthreads();
#pragma unroll 1
    for (int ch = 0; ch < 4; ++ch) {
        if (wv == ch) {
            float gam[8];
#pragma unroll
            for (int a = 0; a < 8; ++a) gam[a] = 0.0f;
#pragma unroll
            for (int a = 0; a < 8; ++a) {
#pragma unroll
                for (int b = 0; b < 8; ++b) {
                    int m0 = (a > b) ? a : b;
                    float s = 0.0f;
#pragma unroll
                    for (int i = 0; i < 8; ++i)
                        if (i >= m0) s = fmaf(M[i][a], M[i][b], s);
                    hn[(a * 8 + b) * 65 + lane] = s;
                    gam[a] = fmaf(s, info[b], gam[a]);
                }
            }
            out[e] = alpha;
            float4* outG = (float4*)(out + (size_t)BATCH + e * 8);
            outG[0] = make_float4(gam[0], gam[1], gam[2], gam[3]);
            outG[1] = make_float4(gam[4], gam[5], gam[6], gam[7]);
        }
        __syncthreads();
        {
            float* outV = out + (size_t)BATCH * 9 + ((size_t)blk * 256 + (size_t)ch * 64) * 64;
#pragma unroll
            for (int i = 0; i < 4; ++i) {
                int g = i * 1024 + t * 4;
                int ee = g >> 6, j = g & 63;
                float4 v = make_float4(hn[(j + 0) * 65 + ee], hn[(j + 1) * 65 + ee],
                                       hn[(j + 2) * 65 + ee], hn[(j + 3) * 65 + ee]);
                *(float4*)(outV + g) = v;
            }
        }
        __syncthreads();
    }
}

extern "C" void kernel_launch(void* const* d_in, const int* in_sizes, int n_in,
                              void* d_out, int out_size, void* d_ws, size_t ws_size,
                              hipStream_t stream) {
    const float* h    = (const float*)d_in[0];
    const float* c    = (const float*)d_in[1];
    const float* zp   = (const float*)d_in[2];
    const float* xt   = (const float*)d_in[3];
    const float* Wk   = (const float*)d_in[4];
    const float* Wr   = (const float*)d_in[5];
    const float* bl   = (const float*)d_in[6];
    const float* Wmu  = (const float*)d_in[7];
    const float* bmu  = (const float*)d_in[8];
    const float* Wls  = (const float*)d_in[9];
    const float* bls  = (const float*)d_in[10];
    const float* Cm   = (const float*)d_in[11];
    const float* bem  = (const float*)d_in[12];
    const float* logR = (const float*)d_in[13];
    float* ws  = (float*)d_ws;
    float* out = (float*)d_out;

    hipLaunchKernelGGL(prep_kernel, dim3(1), dim3(256), 0, stream, Wk, Wr, Cm, logR, ws);
    hipLaunchKernelGGL(lstm_kernel, dim3(BATCH / 64), dim3(256), 0, stream,
                       h, c, zp, bl, ws, out);
    hipLaunchKernelGGL(tail_kernel, dim3(BATCH / 256), dim3(256), 0, stream,
                       xt, Wmu, bmu, Wls, bls, Cm, bem, ws, out);
}

// Round 11
// 136.101 us; speedup vs baseline: 2.7962x; 1.0901x over previous
//
#include <hip/hip_runtime.h>
#include <math.h>

// Problem constants
#define BATCH 262144

// ws layout (float offsets)
#define WA_OFF  0        // [48 frags][64 lanes][8 bf16] A-fragments of W^T (12288 floats)
#define G6_OFF  18944    // [8][8]  C^T diag(1/(R+1e-6)) C
#define G8_OFF  19008    // [8][8]  C^T diag(1/(R+1e-8)) C
#define R6_OFF  19072    // [16] 1/(R+1e-6)
#define R8_OFF  19088    // [16] 1/(R+1e-8)
#define SLR_OFF 19104    // scalar: sum log(R+1e-6)

typedef __attribute__((ext_vector_type(8))) short bf16x8;
typedef __attribute__((ext_vector_type(4))) float f32x4;

__device__ __forceinline__ float rcp1(float x) {
    float r = __builtin_amdgcn_rcpf(x);
    return r * (2.0f - x * r);
}
__device__ __forceinline__ float sigm(float x) {
    float e = __expf(-fabsf(x));
    float s = rcp1(1.0f + e);
    return (x >= 0.0f) ? s : e * s;
}
__device__ __forceinline__ float tanh_f(float x) {
    float e = __expf(-2.0f * fabsf(x));
    float t = (1.0f - e) * rcp1(1.0f + e);
    return copysignf(t, x);
}
__device__ __forceinline__ unsigned rne_bf16(float x) {
    unsigned u = __float_as_uint(x);
    return (u + 0x7fffu + ((u >> 16) & 1u)) >> 16;   // round-to-nearest-even bf16
}
__device__ __forceinline__ unsigned pack2(float lo, float hi) {
    return rne_bf16(lo) | (rne_bf16(hi) << 16);
}

// ---------------- prep: A-fragments (bf16) + batch-independent stats ---------
__global__ void prep_kernel(const float* __restrict__ Wk,   // [8][256]
                            const float* __restrict__ Wr,   // [64][256]
                            const float* __restrict__ Cm,   // [16][8]
                            const float* __restrict__ logR, // [16]
                            float* __restrict__ ws) {
    int t = threadIdx.x;
    unsigned* wa = (unsigned*)(ws + WA_OFF);
#pragma unroll 1
    for (int i = 0; i < 12; ++i) {
        int F  = i * 256 + t;          // 0..3071 = frag(48) x lane(64)
        int fr = F >> 6, l = F & 63;
        int m  = fr / 3, ks = fr % 3;
        int c  = m * 16 + (l & 15);    // gate-interleaved col = u*4+g
        int k0 = ks * 32 + (l >> 4) * 8;
        int src = (c & 3) * 64 + (c >> 2);   // original col g*64+u
        float v[8];
#pragma unroll
        for (int j = 0; j < 8; ++j) {
            int k = k0 + j;
            v[j] = (k < 8) ? Wk[k * 256 + src] : (k < 72 ? Wr[(k - 8) * 256 + src] : 0.0f);
        }
        wa[F * 4 + 0] = pack2(v[0], v[1]);
        wa[F * 4 + 1] = pack2(v[2], v[3]);
        wa[F * 4 + 2] = pack2(v[4], v[5]);
        wa[F * 4 + 3] = pack2(v[6], v[7]);
    }

    if (t < 64) {
        int k = t >> 3, l = t & 7;
        float g6 = 0.0f, g8 = 0.0f;
        for (int i = 0; i < 16; ++i) {
            float R  = expf(logR[i]);
            float cc = Cm[i * 8 + k] * Cm[i * 8 + l];
            g6 += cc / (R + 1e-6f);
            g8 += cc / (R + 1e-8f);
        }
        ws[G6_OFF + t] = g6;
        ws[G8_OFF + t] = g8;
    } else if (t < 80) {
        int i = t - 64;
        float R = expf(logR[i]);
        ws[R6_OFF + i] = 1.0f / (R + 1e-6f);
        ws[R8_OFF + i] = 1.0f / (R + 1e-8f);
    } else if (t == 80) {
        float s = 0.0f;
        for (int i = 0; i < 16; ++i) s += logf(expf(logR[i]) + 1e-6f);
        ws[SLR_OFF] = s;
    }
}

// ---------------- LSTM kernel: MFMA bf16 GEMM + mu/lsg stash -----------------
// Block = 256 thr = 4 waves, 64 elements. D[c][e] = W^T ha^T: M=256 N=64 K=96.
// Wave w: M-tiles 4w..4w+3. 48 mfma_f32_16x16x32_bf16/wave. D layout (m89):
// lane's 4 acc regs = the 4 gates (i,f,g,o) of unit u=16w+4mm+(l>>4) for
// element e=n*16+(l&15). After nonlinearity, mu/log_sigma are computed from
// LDS h_new and stashed in out[B*9 + e*64 + 0..15] (element e's own V slot;
// tail reads then overwrites it -> race-free).
__global__ __launch_bounds__(256)
void lstm_kernel(const float* __restrict__ h_in,
                 const float* __restrict__ c_in,
                 const float* __restrict__ z_prev,
                 const float* __restrict__ b_lstm,
                 const float* __restrict__ W_mu,
                 const float* __restrict__ b_mu,
                 const float* __restrict__ W_ls,
                 const float* __restrict__ b_ls,
                 const float* __restrict__ ws,
                 float* __restrict__ out) {
    __shared__ __align__(16) float r1[64 * 72];  // ha fp32 [e][72]; -> cbuf [e][68]
    __shared__ __align__(16) float r2[64 * 68];  // B-frags (3072 floats); -> hbuf [u][68]

    const int t   = threadIdx.x;
    const int l   = t & 63;
    const int wvu = __builtin_amdgcn_readfirstlane(t >> 6);
    const int lhi = l >> 4, llo = l & 15;
    const size_t E0 = (size_t)blockIdx.x * 64;

    // ---- stage ha fp32 row-major (coalesced, linear LDS writes) ----
#pragma unroll
    for (int i = 0; i < 4; ++i) {
        int g = i * 1024 + t * 4;
        int e = g >> 6, u = g & 63;
        float4 hv = *(const float4*)(h_in + E0 * 64 + g);
        *(float4*)(r1 + e * 72 + 8 + u) = hv;
    }
    if (t < 128) {
        int g = t * 4;
        int e = g >> 3, p = g & 7;
        float4 zv = *(const float4*)(z_prev + E0 * 8 + g);
        *(float4*)(r1 + e * 72 + p) = zv;
    }
    __syncthreads();   // b1: ha staged

    // ---- convert ha -> bf16 B-fragments ----
    unsigned* fr = (unsigned*)r2;
#pragma unroll
    for (int i = 0; i < 3; ++i) {
        int c = i * 256 + t;
        if (c < 576) {                       // 576 chunks of 8 floats (k<72)
            int e = c / 9, k0 = (c % 9) * 8;
            float4 va = *(const float4*)(r1 + c * 8);
            float4 vb = *(const float4*)(r1 + c * 8 + 4);
            uint4 pk;
            pk.x = pack2(va.x, va.y);
            pk.y = pack2(va.z, va.w);
            pk.z = pack2(vb.x, vb.y);
            pk.w = pack2(vb.z, vb.w);
            int n = e >> 4, lo = e & 15, ks = k0 >> 5, hi = (k0 & 31) >> 3;
            int F = (n * 3 + ks) * 64 + hi * 16 + lo;
            *(uint4*)(fr + F * 4) = pk;
        }
    }
    if (t < 192) {                           // zero-pad k = 72..95
        int n = t / 48, r = t % 48;
        int hi = r / 16 + 1, lo = r & 15;
        int F = (n * 3 + 2) * 64 + hi * 16 + lo;
        *(uint4*)(fr + F * 4) = make_uint4(0, 0, 0, 0);
    }
    __syncthreads();   // b2: frags ready; r1 (ha) dead

    // ---- issue c_old loads (latency hides under GEMM) ----
    float4 cp0 = *(const float4*)(c_in + E0 * 64 + 0 * 1024 + t * 4);
    float4 cp1 = *(const float4*)(c_in + E0 * 64 + 1 * 1024 + t * 4);
    float4 cp2 = *(const float4*)(c_in + E0 * 64 + 2 * 1024 + t * 4);
    float4 cp3 = *(const float4*)(c_in + E0 * 64 + 3 * 1024 + t * 4);

    // ---- MFMA GEMM: 48 mfma/wave ----
    f32x4 acc[4][4];
#pragma unroll
    for (int mm = 0; mm < 4; ++mm)
#pragma unroll
        for (int n = 0; n < 4; ++n) acc[mm][n] = (f32x4){0.f, 0.f, 0.f, 0.f};

    const unsigned* WA = (const unsigned*)(ws + WA_OFF);
#pragma unroll
    for (int ks = 0; ks < 3; ++ks) {
        bf16x8 bfr[4], afr[4];
#pragma unroll
        for (int n = 0; n < 4; ++n)
            bfr[n] = *(const bf16x8*)(fr + ((n * 3 + ks) * 64 + l) * 4);
#pragma unroll
        for (int mm = 0; mm < 4; ++mm)
            afr[mm] = *(const bf16x8*)(WA + (((4 * wvu + mm) * 3 + ks) * 64 + l) * 4);
#pragma unroll
        for (int mm = 0; mm < 4; ++mm)
#pragma unroll
            for (int n = 0; n < 4; ++n)
                acc[mm][n] = __builtin_amdgcn_mfma_f32_16x16x32_bf16(
                    afr[mm], bfr[n], acc[mm][n], 0, 0, 0);
    }

    // ---- write cbuf [e][68] (r1 reuse) ----
    float* cbuf = r1;
    {
        int g0 = t * 4;
        *(float4*)(cbuf + ((g0 >> 6)) * 68 + (g0 & 63)) = cp0;
        int g1 = 1024 + t * 4;
        *(float4*)(cbuf + ((g1 >> 6)) * 68 + (g1 & 63)) = cp1;
        int g2 = 2048 + t * 4;
        *(float4*)(cbuf + ((g2 >> 6)) * 68 + (g2 & 63)) = cp2;
        int g3 = 3072 + t * 4;
        *(float4*)(cbuf + ((g3 >> 6)) * 68 + (g3 & 63)) = cp3;
    }
    __syncthreads();   // b3: cbuf staged + all frag reads done

    // ---- nonlinearity: lane owns 4u x 4e x 4 gates ----
    float* hbuf = r2;   // [u][68]
#pragma unroll
    for (int mm = 0; mm < 4; ++mm) {
        int u = 16 * wvu + 4 * mm + lhi;
        float bi = b_lstm[u], bf_ = b_lstm[64 + u], bg = b_lstm[128 + u], bo = b_lstm[192 + u];
#pragma unroll
        for (int n = 0; n < 4; ++n) {
            int e = n * 16 + llo;
            float zi = acc[mm][n][0] + bi;
            float zf = acc[mm][n][1] + bf_;
            float zg = acc[mm][n][2] + bg;
            float zo = acc[mm][n][3] + bo;
            float cold = cbuf[e * 68 + u];
            float cn = sigm(zf) * cold + sigm(zi) * tanh_f(zg);
            float hn = sigm(zo) * tanh_f(cn);
            cbuf[e * 68 + u] = cn;        // own slot
            hbuf[u * 68 + e] = hn;
        }
    }
    __syncthreads();   // b4: hbuf/cbuf final

    // ---- coalesced write-out of h_new / c_new ----
    float* outH = out + (size_t)BATCH * 73  + E0 * 64;
    float* outC = out + (size_t)BATCH * 137 + E0 * 64;
#pragma unroll
    for (int i = 0; i < 4; ++i) {
        int g = i * 1024 + t * 4;
        int e = g >> 6, u = g & 63;
        *(float4*)(outC + g) = *(const float4*)(cbuf + e * 68 + u);
        float4 hv = make_float4(hbuf[(u + 0) * 68 + e], hbuf[(u + 1) * 68 + e],
                                hbuf[(u + 2) * 68 + e], hbuf[(u + 3) * 68 + e]);
        *(float4*)(outH + g) = hv;
    }

    // ---- mu/log_sigma: wave wvu computes outputs 4wvu..4wvu+3 for elem l ----
    // outputs 0-7 = mu (W_mu), 8-15 = lsg (W_ls); stash in elem's V slot.
    {
        const float* Wsel = (wvu < 2) ? W_mu : W_ls;
        const float* bsel = (wvu < 2) ? b_mu : b_ls;
        const int d0 = (wvu & 1) * 4;
        float m0 = bsel[d0 + 0], m1 = bsel[d0 + 1], m2 = bsel[d0 + 2], m3 = bsel[d0 + 3];
#pragma unroll
        for (int u = 0; u < 64; ++u) {
            float hv = hbuf[u * 68 + l];
            m0 = fmaf(hv, Wsel[u * 8 + d0 + 0], m0);
            m1 = fmaf(hv, Wsel[u * 8 + d0 + 1], m1);
            m2 = fmaf(hv, Wsel[u * 8 + d0 + 2], m2);
            m3 = fmaf(hv, Wsel[u * 8 + d0 + 3], m3);
        }
        float* slot = out + (size_t)BATCH * 9 + (E0 + l) * 64 + wvu * 4;
        *(float4*)slot = make_float4(m0, m1, m2, m3);
    }
}

// ---------------- tail kernel: Gaussian tail from stashed mu/lsg -------------
__global__ __launch_bounds__(256)
void tail_kernel(const float* __restrict__ x_in,
                 const float* __restrict__ Cm,
                 const float* __restrict__ b_em,
                 const float* __restrict__ ws,
                 float* __restrict__ out) {
    __shared__ float vbuf[64 * 65];   // V staging per 64-elem chunk

    const int t    = threadIdx.x;
    const int lane = t & 63;
    const int wv   = t >> 6;
    const int blk  = blockIdx.x;
    const size_t e = (size_t)blk * 256 + t;

    const float* G6 = ws + G6_OFF;
    const float* G8 = ws + G8_OFF;
    const float* r6 = ws + R6_OFF;
    const float* r8 = ws + R8_OFF;
    const float  slr = ws[SLR_OFF];

    // ---- read stashed mu/lsg from this element's V slot ----
    const float* tmp = out + (size_t)BATCH * 9 + e * 64;
    float4 q0 = *(const float4*)(tmp + 0);
    float4 q1 = *(const float4*)(tmp + 4);
    float4 q2 = *(const float4*)(tmp + 8);
    float4 q3 = *(const float4*)(tmp + 12);
    float mu[8]  = {q0.x, q0.y, q0.z, q0.w, q1.x, q1.y, q1.z, q1.w};
    float lsg[8] = {q2.x, q2.y, q2.z, q2.w, q3.x, q3.y, q3.z, q3.w};

    float sig[8], Sinv[8];
#pragma unroll
    for (int d = 0; d < 8; ++d) {
        float l = fminf(fmaxf(lsg[d], -5.0f), 3.0f);
        float s = __expf(l);
        sig[d]  = s;
        Sinv[d] = rcp1(s * s + 1e-8f);
    }

    float xv[16];
    {
        const float4* x4 = (const float4*)(x_in + e * 16);
#pragma unroll
        for (int q = 0; q < 4; ++q) {
            float4 v = x4[q];
            xv[4 * q + 0] = v.x; xv[4 * q + 1] = v.y;
            xv[4 * q + 2] = v.z; xv[4 * q + 3] = v.w;
        }
    }

    float t6[8], t8[8];
#pragma unroll
    for (int k = 0; k < 8; ++k) { t6[k] = 0.0f; t8[k] = 0.0f; }
    float qdr = 0.0f;
#pragma unroll
    for (int i = 0; i < 16; ++i) {
        float pm = b_em[i];
#pragma unroll
        for (int d = 0; d < 8; ++d) pm = fmaf(mu[d], Cm[i * 8 + d], pm);
        float df = xv[i] - pm;
        float xe = xv[i] - b_em[i];
        float a6 = df * r6[i];
        float a8 = xe * r8[i];
        qdr = fmaf(df, a6, qdr);
#pragma unroll
        for (int k = 0; k < 8; ++k) {
            t6[k] = fmaf(a6, Cm[i * 8 + k], t6[k]);
            t8[k] = fmaf(a8, Cm[i * 8 + k], t8[k]);
        }
    }

    // ---- alpha via Woodbury ----
    float M[8][8];
#pragma unroll
    for (int k = 0; k < 8; ++k)
#pragma unroll
        for (int l = 0; l <= k; ++l)
            M[k][l] = ((k == l) ? 1.0f : 0.0f) + sig[k] * sig[l] * G6[k * 8 + l];

    float ldia[8];
    float logdetM = 0.0f;
#pragma unroll
    for (int k = 0; k < 8; ++k) {
        float d = M[k][k];
#pragma unroll
        for (int j = 0; j < k; ++j) d = fmaf(-M[k][j], M[k][j], d);
        float l = sqrtf(d);
        logdetM += __logf(d);
        float li = rcp1(l);
        M[k][k] = l; ldia[k] = li;
#pragma unroll
        for (int i = k + 1; i < 8; ++i) {
            float s = M[i][k];
#pragma unroll
            for (int j = 0; j < k; ++j) s = fmaf(-M[i][j], M[k][j], s);
            M[i][k] = s * li;
        }
    }
    float w[8];
    float ssq = 0.0f;
#pragma unroll
    for (int k = 0; k < 8; ++k) {
        float s = sig[k] * t6[k];
#pragma unroll
        for (int j = 0; j < k; ++j) s = fmaf(-M[k][j], w[j], s);
        w[k] = s * ldia[k];
        ssq  = fmaf(w[k], w[k], ssq);
    }
    float mahal  = qdr - ssq;
    float alpha  = -0.5f * (mahal + slr + logdetM + 29.40603306254952f); // 16*ln(2pi)

    // ---- gamma: V = (diag(Sinv)+1e-6 I + G8)^-1 ----
    float Vi[8][8];
#pragma unroll
    for (int k = 0; k < 8; ++k)
#pragma unroll
        for (int l = 0; l <= k; ++l)
            Vi[k][l] = G8[k * 8 + l] + ((k == l) ? (Sinv[k] + 1e-6f) : 0.0f);

    float vdia[8];
#pragma unroll
    for (int k = 0; k < 8; ++k) {
        float d = Vi[k][k];
#pragma unroll
        for (int j = 0; j < k; ++j) d = fmaf(-Vi[k][j], Vi[k][j], d);
        float l = sqrtf(d);
        float li = rcp1(l);
        Vi[k][k] = l; vdia[k] = li;
#pragma unroll
        for (int i = k + 1; i < 8; ++i) {
            float s = Vi[i][k];
#pragma unroll
            for (int j = 0; j < k; ++j) s = fmaf(-Vi[i][j], Vi[k][j], s);
            Vi[i][k] = s * li;
        }
    }
    // J = L^-1 (lower), stored into M (dead)
#pragma unroll
    for (int k = 0; k < 8; ++k) {
        M[k][k] = vdia[k];
#pragma unroll
        for (int i = k + 1; i < 8; ++i) {
            float s = 0.0f;
#pragma unroll
            for (int j = k; j < i; ++j) s = fmaf(Vi[i][j], M[j][k], s);
            M[i][k] = -s * vdia[i];
        }
    }
    float info[8];
#pragma unroll
    for (int k = 0; k < 8; ++k) info[k] = fmaf(Sinv[k], mu[k], t8[k]);

    // ---- V = J^T J + gamma, staged through LDS in 4 chunks ----
    // NOTE: first __syncthreads below drains vmcnt for ALL threads (HIP
    // barrier semantics) -> every thread's temp mu/lsg loads completed
    // before any V-region store. Race-free overwrite of the stash.
#pragma unroll 1
    for (int ch = 0; ch < 4; ++ch) {
        if (wv == ch) {
            float gam[8];
#pragma unroll
            for (int a = 0; a < 8; ++a) gam[a] = 0.0f;
#pragma unroll
            for (int a = 0; a < 8; ++a) {
#pragma unroll
                for (int b = 0; b < 8; ++b) {
                    int m0 = (a > b) ? a : b;
                    float s = 0.0f;
#pragma unroll
                    for (int i = 0; i < 8; ++i)
                        if (i >= m0) s = fmaf(M[i][a], M[i][b], s);
                    vbuf[(a * 8 + b) * 65 + lane] = s;
                    gam[a] = fmaf(s, info[b], gam[a]);
                }
            }
            out[e] = alpha;
            float4* outG = (float4*)(out + (size_t)BATCH + e * 8);
            outG[0] = make_float4(gam[0], gam[1], gam[2], gam[3]);
            outG[1] = make_float4(gam[4], gam[5], gam[6], gam[7]);
        }
        __syncthreads();
        {
            float* outV = out + (size_t)BATCH * 9 + ((size_t)blk * 256 + (size_t)ch * 64) * 64;
#pragma unroll
            for (int i = 0; i < 4; ++i) {
                int g = i * 1024 + t * 4;
                int ee = g >> 6, j = g & 63;
                float4 v = make_float4(vbuf[(j + 0) * 65 + ee], vbuf[(j + 1) * 65 + ee],
                                       vbuf[(j + 2) * 65 + ee], vbuf[(j + 3) * 65 + ee]);
                *(float4*)(outV + g) = v;
            }
        }
        __syncthreads();
    }
}

extern "C" void kernel_launch(void* const* d_in, const int* in_sizes, int n_in,
                              void* d_out, int out_size, void* d_ws, size_t ws_size,
                              hipStream_t stream) {
    const float* h    = (const float*)d_in[0];
    const float* c    = (const float*)d_in[1];
    const float* zp   = (const float*)d_in[2];
    const float* xt   = (const float*)d_in[3];
    const float* Wk   = (const float*)d_in[4];
    const float* Wr   = (const float*)d_in[5];
    const float* bl   = (const float*)d_in[6];
    const float* Wmu  = (const float*)d_in[7];
    const float* bmu  = (const float*)d_in[8];
    const float* Wls  = (const float*)d_in[9];
    const float* bls  = (const float*)d_in[10];
    const float* Cm   = (const float*)d_in[11];
    const float* bem  = (const float*)d_in[12];
    const float* logR = (const float*)d_in[13];
    float* ws  = (float*)d_ws;
    float* out = (float*)d_out;

    hipLaunchKernelGGL(prep_kernel, dim3(1), dim3(256), 0, stream, Wk, Wr, Cm, logR, ws);
    hipLaunchKernelGGL(lstm_kernel, dim3(BATCH / 64), dim3(256), 0, stream,
                       h, c, zp, bl, Wmu, bmu, Wls, bls, ws, out);
    hipLaunchKernelGGL(tail_kernel, dim3(BATCH / 256), dim3(256), 0, stream,
                       xt, Cm, bem, ws, out);
}

// Round 12
// 112.252 us; speedup vs baseline: 3.3903x; 1.2125x over previous
//
#include <hip/hip_runtime.h>
#include <math.h>

// Problem constants
#define BATCH 262144

// ws layout (float offsets)
#define WA_OFF  0        // [48 frags][64 lanes][8 bf16] A-fragments of W^T (12288 floats)
#define G6_OFF  18944    // [8][8]  C^T diag(1/(R+1e-6)) C
#define G8_OFF  19008    // [8][8]  C^T diag(1/(R+1e-8)) C
#define R6_OFF  19072    // [16] 1/(R+1e-6)
#define R8_OFF  19088    // [16] 1/(R+1e-8)
#define SLR_OFF 19104    // scalar: sum log(R+1e-6)

typedef __attribute__((ext_vector_type(8))) short bf16x8;
typedef __attribute__((ext_vector_type(4))) float f32x4;

__device__ __forceinline__ float rcp1(float x) {
    float r = __builtin_amdgcn_rcpf(x);
    return r * (2.0f - x * r);   // Newton step: used in tail only
}
// lstm nonlinearity: raw v_rcp (rel err ~6e-5, invisible vs bf16 GEMM noise)
__device__ __forceinline__ float sigm(float x) {
    float e = __expf(-fabsf(x));
    float s = __builtin_amdgcn_rcpf(1.0f + e);
    return (x >= 0.0f) ? s : e * s;
}
__device__ __forceinline__ float tanh_f(float x) {
    float e = __expf(-2.0f * fabsf(x));
    float t = (1.0f - e) * __builtin_amdgcn_rcpf(1.0f + e);
    return copysignf(t, x);
}
__device__ __forceinline__ unsigned rne_bf16(float x) {
    unsigned u = __float_as_uint(x);
    return (u + 0x7fffu + ((u >> 16) & 1u)) >> 16;   // round-to-nearest-even bf16
}
__device__ __forceinline__ unsigned pack2(float lo, float hi) {
    return rne_bf16(lo) | (rne_bf16(hi) << 16);
}

// ---------------- prep: A-fragments (bf16) + batch-independent stats ---------
// Parallelized: blocks 0..11 each pack one 256-fragment-row chunk (was a
// 12-iteration serial loop in ONE block -> latency-serial, ~10-30us on the
// critical path). Block 12 computes the scalar stats.
__global__ void prep_kernel(const float* __restrict__ Wk,   // [8][256]
                            const float* __restrict__ Wr,   // [64][256]
                            const float* __restrict__ Cm,   // [16][8]
                            const float* __restrict__ logR, // [16]
                            float* __restrict__ ws) {
    int b = blockIdx.x;
    int t = threadIdx.x;
    if (b < 12) {
        unsigned* wa = (unsigned*)(ws + WA_OFF);
        int F  = b * 256 + t;          // 0..3071 = frag(48) x lane(64)
        int fr = F >> 6, l = F & 63;
        int m  = fr / 3, ks = fr % 3;
        int c  = m * 16 + (l & 15);    // gate-interleaved col = u*4+g
        int k0 = ks * 32 + (l >> 4) * 8;
        int src = (c & 3) * 64 + (c >> 2);   // original col g*64+u
        float v[8];
#pragma unroll
        for (int j = 0; j < 8; ++j) {
            int k = k0 + j;
            v[j] = (k < 8) ? Wk[k * 256 + src] : (k < 72 ? Wr[(k - 8) * 256 + src] : 0.0f);
        }
        wa[F * 4 + 0] = pack2(v[0], v[1]);
        wa[F * 4 + 1] = pack2(v[2], v[3]);
        wa[F * 4 + 2] = pack2(v[4], v[5]);
        wa[F * 4 + 3] = pack2(v[6], v[7]);
        return;
    }
    // block 12: batch-independent stats
    if (t < 64) {
        int k = t >> 3, l = t & 7;
        float g6 = 0.0f, g8 = 0.0f;
        for (int i = 0; i < 16; ++i) {
            float R  = expf(logR[i]);
            float cc = Cm[i * 8 + k] * Cm[i * 8 + l];
            g6 += cc / (R + 1e-6f);
            g8 += cc / (R + 1e-8f);
        }
        ws[G6_OFF + t] = g6;
        ws[G8_OFF + t] = g8;
    } else if (t < 80) {
        int i = t - 64;
        float R = expf(logR[i]);
        ws[R6_OFF + i] = 1.0f / (R + 1e-6f);
        ws[R8_OFF + i] = 1.0f / (R + 1e-8f);
    } else if (t == 80) {
        float s = 0.0f;
        for (int i = 0; i < 16; ++i) s += logf(expf(logR[i]) + 1e-6f);
        ws[SLR_OFF] = s;
    }
}

// ---------------- LSTM kernel: MFMA bf16 GEMM + mu/lsg stash -----------------
// Block = 256 thr = 4 waves, 64 elements. D[c][e] = W^T ha^T: M=256 N=64 K=96.
// Wave w: M-tiles 4w..4w+3. 48 mfma_f32_16x16x32_bf16/wave. D layout (m89):
// lane's 4 acc regs = the 4 gates (i,f,g,o) of unit u=16w+4mm+(l>>4) for
// element e=n*16+(l&15). After nonlinearity, mu/log_sigma are computed from
// LDS h_new and stashed in out[B*9 + e*64 + 0..15] (element e's own V slot;
// tail reads then overwrites it -> race-free).
__global__ __launch_bounds__(256)
void lstm_kernel(const float* __restrict__ h_in,
                 const float* __restrict__ c_in,
                 const float* __restrict__ z_prev,
                 const float* __restrict__ b_lstm,
                 const float* __restrict__ W_mu,
                 const float* __restrict__ b_mu,
                 const float* __restrict__ W_ls,
                 const float* __restrict__ b_ls,
                 const float* __restrict__ ws,
                 float* __restrict__ out) {
    __shared__ __align__(16) float r1[64 * 72];  // ha fp32 [e][72]; -> cbuf [e][68]
    __shared__ __align__(16) float r2[64 * 68];  // B-frags (3072 floats); -> hbuf [u][68]

    const int t   = threadIdx.x;
    const int l   = t & 63;
    const int wvu = __builtin_amdgcn_readfirstlane(t >> 6);
    const int lhi = l >> 4, llo = l & 15;
    const size_t E0 = (size_t)blockIdx.x * 64;

    // ---- stage ha fp32 row-major (coalesced, linear LDS writes) ----
#pragma unroll
    for (int i = 0; i < 4; ++i) {
        int g = i * 1024 + t * 4;
        int e = g >> 6, u = g & 63;
        float4 hv = *(const float4*)(h_in + E0 * 64 + g);
        *(float4*)(r1 + e * 72 + 8 + u) = hv;
    }
    if (t < 128) {
        int g = t * 4;
        int e = g >> 3, p = g & 7;
        float4 zv = *(const float4*)(z_prev + E0 * 8 + g);
        *(float4*)(r1 + e * 72 + p) = zv;
    }
    __syncthreads();   // b1: ha staged

    // ---- convert ha -> bf16 B-fragments ----
    unsigned* fr = (unsigned*)r2;
#pragma unroll
    for (int i = 0; i < 3; ++i) {
        int c = i * 256 + t;
        if (c < 576) {                       // 576 chunks of 8 floats (k<72)
            int e = c / 9, k0 = (c % 9) * 8;
            float4 va = *(const float4*)(r1 + c * 8);
            float4 vb = *(const float4*)(r1 + c * 8 + 4);
            uint4 pk;
            pk.x = pack2(va.x, va.y);
            pk.y = pack2(va.z, va.w);
            pk.z = pack2(vb.x, vb.y);
            pk.w = pack2(vb.z, vb.w);
            int n = e >> 4, lo = e & 15, ks = k0 >> 5, hi = (k0 & 31) >> 3;
            int F = (n * 3 + ks) * 64 + hi * 16 + lo;
            *(uint4*)(fr + F * 4) = pk;
        }
    }
    if (t < 192) {                           // zero-pad k = 72..95
        int n = t / 48, r = t % 48;
        int hi = r / 16 + 1, lo = r & 15;
        int F = (n * 3 + 2) * 64 + hi * 16 + lo;
        *(uint4*)(fr + F * 4) = make_uint4(0, 0, 0, 0);
    }
    __syncthreads();   // b2: frags ready; r1 (ha) dead

    // ---- issue c_old loads (latency hides under GEMM) ----
    float4 cp0 = *(const float4*)(c_in + E0 * 64 + 0 * 1024 + t * 4);
    float4 cp1 = *(const float4*)(c_in + E0 * 64 + 1 * 1024 + t * 4);
    float4 cp2 = *(const float4*)(c_in + E0 * 64 + 2 * 1024 + t * 4);
    float4 cp3 = *(const float4*)(c_in + E0 * 64 + 3 * 1024 + t * 4);

    // ---- MFMA GEMM: 48 mfma/wave ----
    f32x4 acc[4][4];
#pragma unroll
    for (int mm = 0; mm < 4; ++mm)
#pragma unroll
        for (int n = 0; n < 4; ++n) acc[mm][n] = (f32x4){0.f, 0.f, 0.f, 0.f};

    const unsigned* WA = (const unsigned*)(ws + WA_OFF);
#pragma unroll
    for (int ks = 0; ks < 3; ++ks) {
        bf16x8 bfr[4], afr[4];
#pragma unroll
        for (int n = 0; n < 4; ++n)
            bfr[n] = *(const bf16x8*)(fr + ((n * 3 + ks) * 64 + l) * 4);
#pragma unroll
        for (int mm = 0; mm < 4; ++mm)
            afr[mm] = *(const bf16x8*)(WA + (((4 * wvu + mm) * 3 + ks) * 64 + l) * 4);
#pragma unroll
        for (int mm = 0; mm < 4; ++mm)
#pragma unroll
            for (int n = 0; n < 4; ++n)
                acc[mm][n] = __builtin_amdgcn_mfma_f32_16x16x32_bf16(
                    afr[mm], bfr[n], acc[mm][n], 0, 0, 0);
    }

    // ---- write cbuf [e][68] (r1 reuse) ----
    float* cbuf = r1;
    {
        int g0 = t * 4;
        *(float4*)(cbuf + ((g0 >> 6)) * 68 + (g0 & 63)) = cp0;
        int g1 = 1024 + t * 4;
        *(float4*)(cbuf + ((g1 >> 6)) * 68 + (g1 & 63)) = cp1;
        int g2 = 2048 + t * 4;
        *(float4*)(cbuf + ((g2 >> 6)) * 68 + (g2 & 63)) = cp2;
        int g3 = 3072 + t * 4;
        *(float4*)(cbuf + ((g3 >> 6)) * 68 + (g3 & 63)) = cp3;
    }
    __syncthreads();   // b3: cbuf staged + all frag reads done

    // ---- nonlinearity: lane owns 4u x 4e x 4 gates ----
    float* hbuf = r2;   // [u][68]
#pragma unroll
    for (int mm = 0; mm < 4; ++mm) {
        int u = 16 * wvu + 4 * mm + lhi;
        float bi = b_lstm[u], bf_ = b_lstm[64 + u], bg = b_lstm[128 + u], bo = b_lstm[192 + u];
#pragma unroll
        for (int n = 0; n < 4; ++n) {
            int e = n * 16 + llo;
            float zi = acc[mm][n][0] + bi;
            float zf = acc[mm][n][1] + bf_;
            float zg = acc[mm][n][2] + bg;
            float zo = acc[mm][n][3] + bo;
            float cold = cbuf[e * 68 + u];
            float cn = sigm(zf) * cold + sigm(zi) * tanh_f(zg);
            float hn = sigm(zo) * tanh_f(cn);
            cbuf[e * 68 + u] = cn;        // own slot
            hbuf[u * 68 + e] = hn;
        }
    }
    __syncthreads();   // b4: hbuf/cbuf final

    // ---- coalesced write-out of h_new / c_new ----
    float* outH = out + (size_t)BATCH * 73  + E0 * 64;
    float* outC = out + (size_t)BATCH * 137 + E0 * 64;
#pragma unroll
    for (int i = 0; i < 4; ++i) {
        int g = i * 1024 + t * 4;
        int e = g >> 6, u = g & 63;
        *(float4*)(outC + g) = *(const float4*)(cbuf + e * 68 + u);
        float4 hv = make_float4(hbuf[(u + 0) * 68 + e], hbuf[(u + 1) * 68 + e],
                                hbuf[(u + 2) * 68 + e], hbuf[(u + 3) * 68 + e]);
        *(float4*)(outH + g) = hv;
    }

    // ---- mu/log_sigma: wave wvu computes outputs 4wvu..4wvu+3 for elem l ----
    // outputs 0-7 = mu (W_mu), 8-15 = lsg (W_ls); stash in elem's V slot.
    {
        const float* Wsel = (wvu < 2) ? W_mu : W_ls;
        const float* bsel = (wvu < 2) ? b_mu : b_ls;
        const int d0 = (wvu & 1) * 4;
        float m0 = bsel[d0 + 0], m1 = bsel[d0 + 1], m2 = bsel[d0 + 2], m3 = bsel[d0 + 3];
#pragma unroll
        for (int u = 0; u < 64; ++u) {
            float hv = hbuf[u * 68 + l];
            m0 = fmaf(hv, Wsel[u * 8 + d0 + 0], m0);
            m1 = fmaf(hv, Wsel[u * 8 + d0 + 1], m1);
            m2 = fmaf(hv, Wsel[u * 8 + d0 + 2], m2);
            m3 = fmaf(hv, Wsel[u * 8 + d0 + 3], m3);
        }
        float* slot = out + (size_t)BATCH * 9 + (E0 + l) * 64 + wvu * 4;
        *(float4*)slot = make_float4(m0, m1, m2, m3);
    }
}

// ---------------- tail kernel: Gaussian tail from stashed mu/lsg -------------
__global__ __launch_bounds__(256)
void tail_kernel(const float* __restrict__ x_in,
                 const float* __restrict__ Cm,
                 const float* __restrict__ b_em,
                 const float* __restrict__ ws,
                 float* __restrict__ out) {
    __shared__ float vbuf[64 * 65];   // V staging per 64-elem chunk

    const int t    = threadIdx.x;
    const int lane = t & 63;
    const int wv   = t >> 6;
    const int blk  = blockIdx.x;
    const size_t e = (size_t)blk * 256 + t;

    const float* G6 = ws + G6_OFF;
    const float* G8 = ws + G8_OFF;
    const float* r6 = ws + R6_OFF;
    const float* r8 = ws + R8_OFF;
    const float  slr = ws[SLR_OFF];

    // ---- read stashed mu/lsg from this element's V slot ----
    const float* tmp = out + (size_t)BATCH * 9 + e * 64;
    float4 q0 = *(const float4*)(tmp + 0);
    float4 q1 = *(const float4*)(tmp + 4);
    float4 q2 = *(const float4*)(tmp + 8);
    float4 q3 = *(const float4*)(tmp + 12);
    float mu[8]  = {q0.x, q0.y, q0.z, q0.w, q1.x, q1.y, q1.z, q1.w};
    float lsg[8] = {q2.x, q2.y, q2.z, q2.w, q3.x, q3.y, q3.z, q3.w};

    float sig[8], Sinv[8];
#pragma unroll
    for (int d = 0; d < 8; ++d) {
        float l = fminf(fmaxf(lsg[d], -5.0f), 3.0f);
        float s = __expf(l);
        sig[d]  = s;
        Sinv[d] = rcp1(s * s + 1e-8f);
    }

    float xv[16];
    {
        const float4* x4 = (const float4*)(x_in + e * 16);
#pragma unroll
        for (int q = 0; q < 4; ++q) {
            float4 v = x4[q];
            xv[4 * q + 0] = v.x; xv[4 * q + 1] = v.y;
            xv[4 * q + 2] = v.z; xv[4 * q + 3] = v.w;
        }
    }

    float t6[8], t8[8];
#pragma unroll
    for (int k = 0; k < 8; ++k) { t6[k] = 0.0f; t8[k] = 0.0f; }
    float qdr = 0.0f;
#pragma unroll
    for (int i = 0; i < 16; ++i) {
        float pm = b_em[i];
#pragma unroll
        for (int d = 0; d < 8; ++d) pm = fmaf(mu[d], Cm[i * 8 + d], pm);
        float df = xv[i] - pm;
        float xe = xv[i] - b_em[i];
        float a6 = df * r6[i];
        float a8 = xe * r8[i];
        qdr = fmaf(df, a6, qdr);
#pragma unroll
        for (int k = 0; k < 8; ++k) {
            t6[k] = fmaf(a6, Cm[i * 8 + k], t6[k]);
            t8[k] = fmaf(a8, Cm[i * 8 + k], t8[k]);
        }
    }

    // ---- alpha via Woodbury ----
    float M[8][8];
#pragma unroll
    for (int k = 0; k < 8; ++k)
#pragma unroll
        for (int l = 0; l <= k; ++l)
            M[k][l] = ((k == l) ? 1.0f : 0.0f) + sig[k] * sig[l] * G6[k * 8 + l];

    float ldia[8];
    float logdetM = 0.0f;
#pragma unroll
    for (int k = 0; k < 8; ++k) {
        float d = M[k][k];
#pragma unroll
        for (int j = 0; j < k; ++j) d = fmaf(-M[k][j], M[k][j], d);
        float l = sqrtf(d);
        logdetM += __logf(d);
        float li = rcp1(l);
        M[k][k] = l; ldia[k] = li;
#pragma unroll
        for (int i = k + 1; i < 8; ++i) {
            float s = M[i][k];
#pragma unroll
            for (int j = 0; j < k; ++j) s = fmaf(-M[i][j], M[k][j], s);
            M[i][k] = s * li;
        }
    }
    float w[8];
    float ssq = 0.0f;
#pragma unroll
    for (int k = 0; k < 8; ++k) {
        float s = sig[k] * t6[k];
#pragma unroll
        for (int j = 0; j < k; ++j) s = fmaf(-M[k][j], w[j], s);
        w[k] = s * ldia[k];
        ssq  = fmaf(w[k], w[k], ssq);
    }
    float mahal  = qdr - ssq;
    float alpha  = -0.5f * (mahal + slr + logdetM + 29.40603306254952f); // 16*ln(2pi)

    // ---- gamma: V = (diag(Sinv)+1e-6 I + G8)^-1 ----
    float Vi[8][8];
#pragma unroll
    for (int k = 0; k < 8; ++k)
#pragma unroll
        for (int l = 0; l <= k; ++l)
            Vi[k][l] = G8[k * 8 + l] + ((k == l) ? (Sinv[k] + 1e-6f) : 0.0f);

    float vdia[8];
#pragma unroll
    for (int k = 0; k < 8; ++k) {
        float d = Vi[k][k];
#pragma unroll
        for (int j = 0; j < k; ++j) d = fmaf(-Vi[k][j], Vi[k][j], d);
        float l = sqrtf(d);
        float li = rcp1(l);
        Vi[k][k] = l; vdia[k] = li;
#pragma unroll
        for (int i = k + 1; i < 8; ++i) {
            float s = Vi[i][k];
#pragma unroll
            for (int j = 0; j < k; ++j) s = fmaf(-Vi[i][j], Vi[k][j], s);
            Vi[i][k] = s * li;
        }
    }
    // J = L^-1 (lower), stored into M (dead)
#pragma unroll
    for (int k = 0; k < 8; ++k) {
        M[k][k] = vdia[k];
#pragma unroll
        for (int i = k + 1; i < 8; ++i) {
            float s = 0.0f;
#pragma unroll
            for (int j = k; j < i; ++j) s = fmaf(Vi[i][j], M[j][k], s);
            M[i][k] = -s * vdia[i];
        }
    }
    float info[8];
#pragma unroll
    for (int k = 0; k < 8; ++k) info[k] = fmaf(Sinv[k], mu[k], t8[k]);

    // ---- V = J^T J + gamma, staged through LDS in 4 chunks ----
    // NOTE: first __syncthreads below drains vmcnt for ALL threads (HIP
    // barrier semantics) -> every thread's temp mu/lsg loads completed
    // before any V-region store. Race-free overwrite of the stash.
#pragma unroll 1
    for (int ch = 0; ch < 4; ++ch) {
        if (wv == ch) {
            float gam[8];
#pragma unroll
            for (int a = 0; a < 8; ++a) gam[a] = 0.0f;
#pragma unroll
            for (int a = 0; a < 8; ++a) {
#pragma unroll
                for (int b = 0; b < 8; ++b) {
                    int m0 = (a > b) ? a : b;
                    float s = 0.0f;
#pragma unroll
                    for (int i = 0; i < 8; ++i)
                        if (i >= m0) s = fmaf(M[i][a], M[i][b], s);
                    vbuf[(a * 8 + b) * 65 + lane] = s;
                    gam[a] = fmaf(s, info[b], gam[a]);
                }
            }
            out[e] = alpha;
            float4* outG = (float4*)(out + (size_t)BATCH + e * 8);
            outG[0] = make_float4(gam[0], gam[1], gam[2], gam[3]);
            outG[1] = make_float4(gam[4], gam[5], gam[6], gam[7]);
        }
        __syncthreads();
        {
            float* outV = out + (size_t)BATCH * 9 + ((size_t)blk * 256 + (size_t)ch * 64) * 64;
#pragma unroll
            for (int i = 0; i < 4; ++i) {
                int g = i * 1024 + t * 4;
                int ee = g >> 6, j = g & 63;
                float4 v = make_float4(vbuf[(j + 0) * 65 + ee], vbuf[(j + 1) * 65 + ee],
                                       vbuf[(j + 2) * 65 + ee], vbuf[(j + 3) * 65 + ee]);
                *(float4*)(outV + g) = v;
            }
        }
        __syncthreads();
    }
}

extern "C" void kernel_launch(void* const* d_in, const int* in_sizes, int n_in,
                              void* d_out, int out_size, void* d_ws, size_t ws_size,
                              hipStream_t stream) {
    const float* h    = (const float*)d_in[0];
    const float* c    = (const float*)d_in[1];
    const float* zp   = (const float*)d_in[2];
    const float* xt   = (const float*)d_in[3];
    const float* Wk   = (const float*)d_in[4];
    const float* Wr   = (const float*)d_in[5];
    const float* bl   = (const float*)d_in[6];
    const float* Wmu  = (const float*)d_in[7];
    const float* bmu  = (const float*)d_in[8];
    const float* Wls  = (const float*)d_in[9];
    const float* bls  = (const float*)d_in[10];
    const float* Cm   = (const float*)d_in[11];
    const float* bem  = (const float*)d_in[12];
    const float* logR = (const float*)d_in[13];
    float* ws  = (float*)d_ws;
    float* out = (float*)d_out;

    hipLaunchKernelGGL(prep_kernel, dim3(13), dim3(256), 0, stream, Wk, Wr, Cm, logR, ws);
    hipLaunchKernelGGL(lstm_kernel, dim3(BATCH / 64), dim3(256), 0, stream,
                       h, c, zp, bl, Wmu, bmu, Wls, bls, ws, out);
    hipLaunchKernelGGL(tail_kernel, dim3(BATCH / 256), dim3(256), 0, stream,
                       xt, Cm, bem, ws, out);
}